// Round 17
// baseline (207.791 us; speedup 1.0000x reference)
//
#include <hip/hip_runtime.h>
#include <stdint.h>

#define CHS 589824           // W*H*Z
#define ROWS 18432           // B*W*H
#define WHn 9216             // W*H
#define NRED 1179648.0f      // B*W*H*Z
#define LOG2E 1.4426950408889634f

typedef short s16x8 __attribute__((ext_vector_type(8)));
typedef float f32x4v __attribute__((ext_vector_type(4)));

#define MFMA16 __builtin_amdgcn_mfma_f32_16x16x32_bf16

// ws layout (bytes): [0,10240) weight frags ; then part (ROWS*256 f32) / part2 / sc
#define WSFRAG 10240

// LDS (block = 2 rows pipelined, 128 threads = 2 waves; each wave owns 2 z-tiles)
#define OXH 0        // X bf16 [z=64][ hi c:32 (64B) | lo c:32 (64B) ] stride 136 (8704)
#define OP  8704     // P_hi bf16 [y=64][p:36] stride 72 (4608)
#define OG  13312    // G bf16 [c=32][pg:68] stride 136 (4352)
#define LDSZ 17664   // 9 blocks/CU (LDS-capped), 18 waves/CU

static __device__ __forceinline__ uint16_t bfh(float v) {
    union { __bf16 h; uint16_t u; } c; c.h = (__bf16)v; return c.u;
}
static __device__ __forceinline__ float bf2f(uint16_t u) {
    union { uint32_t x; float f; } c; c.x = (uint32_t)u << 16; return c.f;
}
static __device__ __forceinline__ uint32_t pk2u(uint16_t a, uint16_t b) {
    return (uint32_t)a | ((uint32_t)b << 16);
}
static __device__ __forceinline__ uint32_t pkbf(float a, float b) {
    return pk2u(bfh(a), bfh(b));
}
static __device__ __forceinline__ float ex2(float x) {
    float r;
    asm("v_exp_f32 %0, %1" : "=v"(r) : "v"(x));
    return r;
}
// 16B from 8B-aligned LDS as two b64s
static __device__ __forceinline__ s16x8 rd8(const char* p) {
    union { uint64_t q[2]; s16x8 s; } v;
    v.q[0] = *(const uint64_t*)p;
    v.q[1] = *(const uint64_t*)(p + 8);
    return v.s;
}

// identity-k hi+lo A-frags of row-major [32][32] f32 weights, optional pre-scale
static __device__ __forceinline__ void wfrag2(const float* __restrict__ Wp, int mt, int l15, int kb,
                                              float sc, s16x8& hi, s16x8& lo) {
    const float* p = Wp + (l15 + 16*mt)*32 + 8*kb;
    const float4 f0 = *(const float4*)p;
    const float4 f1 = *(const float4*)(p + 4);
    float f[8] = {f0.x*sc, f0.y*sc, f0.z*sc, f0.w*sc, f1.x*sc, f1.y*sc, f1.z*sc, f1.w*sc};
    union { uint32_t u[4]; s16x8 v; } rh, rl;
    #pragma unroll
    for (int i = 0; i < 4; ++i) {
        const uint16_t h0 = bfh(f[2*i]), h1 = bfh(f[2*i+1]);
        rh.u[i] = pk2u(h0, h1);
        rl.u[i] = pk2u(bfh(f[2*i] - bf2f(h0)), bfh(f[2*i+1] - bf2f(h1)));
    }
    hi = rh.v; lo = rl.v;
}
// c-permuted A-frag for W (slot j <-> c = 16*(j>>2) + 4*kb + (j&3))
static __device__ __forceinline__ s16x8 wfragW(const float* __restrict__ Wp, int mt, int l15, int kb) {
    const float* p = Wp + (l15 + 16*mt)*32;
    const float4 f0 = *(const float4*)(p + 4*kb);
    const float4 f1 = *(const float4*)(p + 16 + 4*kb);
    union { uint32_t u[4]; s16x8 v; } r;
    r.u[0] = pkbf(f0.x, f0.y); r.u[1] = pkbf(f0.z, f0.w);
    r.u[2] = pkbf(f1.x, f1.y); r.u[3] = pkbf(f1.z, f1.w);
    return r.v;
}

// k0: one block, precompute weight fragments into ws (theta scaled by LOG2E)
__global__ __launch_bounds__(256) void k0_frag(
    const float* __restrict__ theta_w, const float* __restrict__ phi_w,
    const float* __restrict__ Ww, char* __restrict__ ws)
{
    const int tid = threadIdx.x;
    const int m = tid >> 7;            // 0 = theta, 1 = phi
    const int r = tid & 127;
    const int mt = r >> 6, l = r & 63;
    s16x8 hi, lo;
    wfrag2(m ? phi_w : theta_w, mt, l & 15, l >> 4, m ? 1.0f : LOG2E, hi, lo);
    *(s16x8*)(ws + m*4096 + (mt*64 + l)*16)        = hi;
    *(s16x8*)(ws + m*4096 + 2048 + (mt*64 + l)*16) = lo;
    if (tid < 128) {
        const int mtw = tid >> 6, lw = tid & 63;
        *(s16x8*)(ws + 8192 + (mtw*64 + lw)*16) = wfragW(Ww, mtw, lw & 15, lw >> 4);
    }
}

__global__ __launch_bounds__(128, 4) void k1_row(
    const float* __restrict__ x, const float* __restrict__ spacings,
    const float* __restrict__ theta_b, const float* __restrict__ phi_b,
    const float* __restrict__ g_w, const float* __restrict__ g_b,
    const float* __restrict__ Wb, const char* __restrict__ frags,
    float* __restrict__ out, float* __restrict__ part)
{
    __shared__ __align__(16) char lds[LDSZ];
    const int t = threadIdx.x;
    const int wv = t >> 6, l = t & 63;       // wv in {0,1}
    const int l15 = l & 15, kb = l >> 4;
    const int row0 = blockIdx.x*2;           // rows row0, row0+1 (same b: WHn even)
    const int b = row0 / WHn, wh = row0 - b*WHn;
    const long base = (long)b*32*CHS + (long)wh*64;
    const bool msk = spacings[b*3 + 2] <= 1.5f;

    // prologue: issue row 0's 16 loads (coalesced 256B lines per channel)
    float xv[2][16];
    #pragma unroll
    for (int j = 0; j < 16; ++j) xv[0][j] = x[base + (long)(16*wv + j)*CHS + l];

    #pragma unroll
    for (int it = 0; it < 2; ++it) {
        // ===== phase 0: pack X hi|lo -> LDS, G via shfl -> LDS =====
        {
            #pragma unroll
            for (int j = 0; j < 8; ++j) {
                const int c0 = 16*wv + 2*j;
                const uint16_t h0 = bfh(xv[it][2*j]), h1 = bfh(xv[it][2*j+1]);
                *(uint32_t*)(lds + OXH + l*136 + c0*2)      = pk2u(h0, h1);
                *(uint32_t*)(lds + OXH + l*136 + 64 + c0*2) =
                    pk2u(bfh(xv[it][2*j] - bf2f(h0)), bfh(xv[it][2*j+1] - bf2f(h1)));
            }
            const int pG = 32*(l >> 5) + 8*((l >> 2) & 3) + 4*((l >> 4) & 1) + (l & 3);
            #pragma unroll
            for (int j = 0; j < 16; ++j) {
                const int c = 16*wv + j;
                float xm = __shfl_up(xv[it][j], 1);    if (l == 0)  xm = 0.f;
                float xp2 = __shfl_down(xv[it][j], 1); if (l == 63) xp2 = 0.f;
                const float g = g_w[3*c]*xm + g_w[3*c+1]*xv[it][j] + g_w[3*c+2]*xp2 + g_b[c];
                *(uint16_t*)(lds + OG + c*136 + 2*pG) = bfh(g);
            }
        }
        __syncthreads();   // B1

        // ===== phase 1: own 2 z-tiles: T kept in regs, P (hi) -> LDS =====
        s16x8 bth[2], btl[2];
        {
            s16x8 bxh[2], bxl[2];
            #pragma unroll
            for (int nt = 0; nt < 2; ++nt) {
                const int zr = 32*wv + 16*nt + l15;
                bxh[nt] = rd8(lds + OXH + zr*136 + 16*kb);
                bxl[nt] = rd8(lds + OXH + zr*136 + 64 + 16*kb);
            }
            // ---- theta pass ----
            {
                const s16x8 t0h = *(const s16x8*)(frags + l*16);
                const s16x8 t1h = *(const s16x8*)(frags + 1024 + l*16);
                const s16x8 t0l = *(const s16x8*)(frags + 2048 + l*16);
                const s16x8 t1l = *(const s16x8*)(frags + 3072 + l*16);
                const float4 b0 = *(const float4*)(theta_b + 4*kb);
                const float4 b1 = *(const float4*)(theta_b + 16 + 4*kb);
                #pragma unroll
                for (int nt = 0; nt < 2; ++nt) {
                    f32x4v T0; T0[0]=b0.x*LOG2E; T0[1]=b0.y*LOG2E; T0[2]=b0.z*LOG2E; T0[3]=b0.w*LOG2E;
                    f32x4v T1; T1[0]=b1.x*LOG2E; T1[1]=b1.y*LOG2E; T1[2]=b1.z*LOG2E; T1[3]=b1.w*LOG2E;
                    T0 = MFMA16(t0h, bxh[nt], T0, 0, 0, 0);
                    T0 = MFMA16(t0h, bxl[nt], T0, 0, 0, 0);
                    T0 = MFMA16(t0l, bxh[nt], T0, 0, 0, 0);
                    T1 = MFMA16(t1h, bxh[nt], T1, 0, 0, 0);
                    T1 = MFMA16(t1h, bxl[nt], T1, 0, 0, 0);
                    T1 = MFMA16(t1l, bxh[nt], T1, 0, 0, 0);
                    uint16_t h[8];
                    #pragma unroll
                    for (int r = 0; r < 4; ++r) { h[r] = bfh(T0[r]); h[4+r] = bfh(T1[r]); }
                    union { uint32_t u[4]; s16x8 s; } H, L2;
                    H.u[0] = pk2u(h[0], h[1]); H.u[1] = pk2u(h[2], h[3]);
                    H.u[2] = pk2u(h[4], h[5]); H.u[3] = pk2u(h[6], h[7]);
                    L2.u[0] = pkbf(T0[0]-bf2f(h[0]), T0[1]-bf2f(h[1]));
                    L2.u[1] = pkbf(T0[2]-bf2f(h[2]), T0[3]-bf2f(h[3]));
                    L2.u[2] = pkbf(T1[0]-bf2f(h[4]), T1[1]-bf2f(h[5]));
                    L2.u[3] = pkbf(T1[2]-bf2f(h[6]), T1[3]-bf2f(h[7]));
                    bth[nt] = H.s; btl[nt] = L2.s;
                }
            }
            // ---- phi pass ----
            {
                const s16x8 p0h = *(const s16x8*)(frags + 4096 + l*16);
                const s16x8 p1h = *(const s16x8*)(frags + 4096 + 1024 + l*16);
                const s16x8 p0l = *(const s16x8*)(frags + 4096 + 2048 + l*16);
                const s16x8 p1l = *(const s16x8*)(frags + 4096 + 3072 + l*16);
                const float4 c0 = *(const float4*)(phi_b + 4*kb);
                const float4 c1 = *(const float4*)(phi_b + 16 + 4*kb);
                #pragma unroll
                for (int nt = 0; nt < 2; ++nt) {
                    const int zr = 32*wv + 16*nt + l15;
                    f32x4v P0; P0[0]=c0.x; P0[1]=c0.y; P0[2]=c0.z; P0[3]=c0.w;
                    f32x4v P1; P1[0]=c1.x; P1[1]=c1.y; P1[2]=c1.z; P1[3]=c1.w;
                    P0 = MFMA16(p0h, bxh[nt], P0, 0, 0, 0);
                    P0 = MFMA16(p0h, bxl[nt], P0, 0, 0, 0);
                    P0 = MFMA16(p0l, bxh[nt], P0, 0, 0, 0);
                    P1 = MFMA16(p1h, bxh[nt], P1, 0, 0, 0);
                    P1 = MFMA16(p1h, bxl[nt], P1, 0, 0, 0);
                    P1 = MFMA16(p1l, bxh[nt], P1, 0, 0, 0);
                    union { uint32_t u[2]; uint64_t q; } w;
                    w.u[0] = pkbf(P0[0], P0[1]); w.u[1] = pkbf(P0[2], P0[3]);
                    *(uint64_t*)(lds + OP + zr*72 + 16*kb) = w.q;
                    w.u[0] = pkbf(P1[0], P1[1]); w.u[1] = pkbf(P1[2], P1[3]);
                    *(uint64_t*)(lds + OP + zr*72 + 16*kb + 8) = w.q;
                }
            }
        }
        __syncthreads();   // B2 (P complete)

        // ===== pipeline: issue next row's loads; latency hides under phases 2-3 =====
        if (it == 0) {
            #pragma unroll
            for (int j = 0; j < 16; ++j)
                xv[1][j] = x[base + 64 + (long)(16*wv + j)*CHS + l];
        }

        // ===== phase 2a: F' = P^T * (T_hi + T_lo), both z-tiles =====
        f32x4v Fq[2][4];
        __builtin_amdgcn_s_setprio(1);
        #pragma unroll
        for (int yt = 0; yt < 4; ++yt) {
            const s16x8 pah = rd8(lds + OP + (16*yt + l15)*72 + 16*kb);
            #pragma unroll
            for (int nt = 0; nt < 2; ++nt) {
                f32x4v zz; zz[0]=0.f; zz[1]=0.f; zz[2]=0.f; zz[3]=0.f;
                zz = MFMA16(pah, bth[nt], zz, 0, 0, 0);
                zz = MFMA16(pah, btl[nt], zz, 0, 0, 0);
                Fq[nt][yt] = zz;
            }
        }
        __builtin_amdgcn_s_setprio(0);

        // ===== phase 2b: softmax via exp2 (unnormalized), pack A' frags =====
        s16x8 apk[2][2];
        float inv[2];
        #pragma unroll
        for (int nt = 0; nt < 2; ++nt) {
            float mx = -3.4e38f;
            #pragma unroll
            for (int yt = 0; yt < 4; ++yt)
                #pragma unroll
                for (int r = 0; r < 4; ++r) mx = fmaxf(mx, Fq[nt][yt][r]);
            mx = fmaxf(mx, __shfl_xor(mx, 16));
            mx = fmaxf(mx, __shfl_xor(mx, 32));
            float p[4][4]; float sum = 0.f;
            #pragma unroll
            for (int yt = 0; yt < 4; ++yt)
                #pragma unroll
                for (int r = 0; r < 4; ++r) { p[yt][r] = ex2(Fq[nt][yt][r] - mx); sum += p[yt][r]; }
            sum += __shfl_xor(sum, 16);
            sum += __shfl_xor(sum, 32);
            inv[nt] = 1.0f / sum;
            #pragma unroll
            for (int ks = 0; ks < 2; ++ks) {
                union { uint32_t u[4]; s16x8 s; } A;
                A.u[0] = pkbf(p[2*ks][0],   p[2*ks][1]);
                A.u[1] = pkbf(p[2*ks][2],   p[2*ks][3]);
                A.u[2] = pkbf(p[2*ks+1][0], p[2*ks+1][1]);
                A.u[3] = pkbf(p[2*ks+1][2], p[2*ks+1][3]);
                apk[nt][ks] = A.s;
            }
        }

        // ===== phase 3: Y = G*A'^T, rescale+residual(+mask), R frag =====
        s16x8 brf[2];
        #pragma unroll
        for (int nt = 0; nt < 2; ++nt) {
            const int zr = 32*wv + 16*nt + l15;
            f32x4v Yq[2];
            #pragma unroll
            for (int r = 0; r < 4; ++r) { Yq[0][r] = 0.f; Yq[1][r] = 0.f; }
            __builtin_amdgcn_s_setprio(1);
            #pragma unroll
            for (int ks = 0; ks < 2; ++ks) {
                #pragma unroll
                for (int mt = 0; mt < 2; ++mt) {
                    const s16x8 gA = rd8(lds + OG + (16*mt + l15)*136 + 64*ks + 16*kb);
                    Yq[mt] = MFMA16(gA, apk[nt][ks], Yq[mt], 0, 0, 0);
                }
            }
            __builtin_amdgcn_s_setprio(0);
            union { uint32_t u[4]; s16x8 s; } R;
            #pragma unroll
            for (int mt = 0; mt < 2; ++mt) {
                const uint64_t xh = *(const uint64_t*)(lds + OXH + zr*136 + (16*mt + 4*kb)*2);
                float rv[4];
                #pragma unroll
                for (int r = 0; r < 4; ++r) {
                    const float xr = bf2f((uint16_t)(xh >> (16*r)));
                    rv[r] = msk ? fmaf(Yq[mt][r], inv[nt], xr) : xr;
                }
                R.u[2*mt]   = pkbf(rv[0], rv[1]);
                R.u[2*mt+1] = pkbf(rv[2], rv[3]);
            }
            brf[nt] = R.s;
        }
        // all LDS reads for this row are done; next iteration repacks X/G after B3.
        if (it == 0) __syncthreads();   // B3 (phase 4 touches no LDS -> overlaps)

        // ===== phase 4: O = W*R + wb -> global; BN partials -> part =====
        {
            const s16x8 aW0 = *(const s16x8*)(frags + 8192 + l*16);
            const s16x8 aW1 = *(const s16x8*)(frags + 8192 + (64 + l)*16);
            const float4 wb0 = *(const float4*)(Wb + 4*kb);
            const float4 wb1 = *(const float4*)(Wb + 16 + 4*kb);
            #pragma unroll
            for (int nt = 0; nt < 2; ++nt) {
                const int zr = 32*wv + 16*nt + l15;
                f32x4v accs[2];
                f32x4v a0; a0[0]=wb0.x; a0[1]=wb0.y; a0[2]=wb0.z; a0[3]=wb0.w;
                f32x4v a1; a1[0]=wb1.x; a1[1]=wb1.y; a1[2]=wb1.z; a1[3]=wb1.w;
                __builtin_amdgcn_s_setprio(1);
                accs[0] = MFMA16(aW0, brf[nt], a0, 0, 0, 0);
                accs[1] = MFMA16(aW1, brf[nt], a1, 0, 0, 0);
                __builtin_amdgcn_s_setprio(0);
                float* op = out + base + it*64 + zr;
                #pragma unroll
                for (int mt = 0; mt < 2; ++mt)
                    #pragma unroll
                    for (int r = 0; r < 4; ++r)
                        op[(long)(16*mt + 4*kb + r)*CHS] = accs[mt][r];
                const int sr = (row0 + it)*4 + 2*wv + nt;
                float bs[8];
                #pragma unroll
                for (int mt = 0; mt < 2; ++mt)
                    #pragma unroll
                    for (int r = 0; r < 4; ++r) bs[4*mt+r] = accs[mt][r];
                #pragma unroll
                for (int off = 1; off < 16; off <<= 1)
                    #pragma unroll
                    for (int i = 0; i < 8; ++i) bs[i] += __shfl_xor(bs[i], off);
                if (l15 == 0) {
                    #pragma unroll
                    for (int mt = 0; mt < 2; ++mt)
                        #pragma unroll
                        for (int r = 0; r < 4; ++r)
                            part[sr*64 + 16*mt + 4*kb + r] = bs[4*mt+r];
                }
                #pragma unroll
                for (int mt = 0; mt < 2; ++mt)
                    #pragma unroll
                    for (int r = 0; r < 4; ++r) { const float v = accs[mt][r]; bs[4*mt+r] = v*v; }
                #pragma unroll
                for (int off = 1; off < 16; off <<= 1)
                    #pragma unroll
                    for (int i = 0; i < 8; ++i) bs[i] += __shfl_xor(bs[i], off);
                if (l15 == 0) {
                    #pragma unroll
                    for (int mt = 0; mt < 2; ++mt)
                        #pragma unroll
                        for (int r = 0; r < 4; ++r)
                            part[sr*64 + 32 + 16*mt + 4*kb + r] = bs[4*mt+r];
                }
            }
        }
    }
}

// stage 2a: 256 blocks, each reduces 288 sub-rows (= 72 rows x 4 z-tiles)
__global__ __launch_bounds__(256) void k2a(const float* __restrict__ part,
                                           float* __restrict__ part2)
{
    __shared__ float red[4][64];
    const int t = threadIdx.x, lane = t & 63, grp = t >> 6;
    const int p = blockIdx.x;
    float s = 0.f;
    for (int k = 0; k < 72; ++k) s += part[(p*288 + grp + 4*k)*64 + lane];
    red[grp][lane] = s;
    __syncthreads();
    if (t < 64) part2[p*64 + t] = red[0][t] + red[1][t] + red[2][t] + red[3][t];
}

// stage 2b: final reduce + BN scale/shift
__global__ __launch_bounds__(256) void k2b(const float* __restrict__ part2,
    const float* __restrict__ gamma, const float* __restrict__ beta,
    float* __restrict__ sc)
{
    __shared__ float red[4][64];
    __shared__ float tot[64];
    const int t = threadIdx.x, lane = t & 63, grp = t >> 6;
    float s = 0.f;
    for (int k = 0; k < 64; ++k) s += part2[(grp + 4*k)*64 + lane];
    red[grp][lane] = s;
    __syncthreads();
    if (t < 64) tot[t] = red[0][t] + red[1][t] + red[2][t] + red[3][t];
    __syncthreads();
    if (t < 32) {
        const float mean = tot[t] / NRED;
        const float var  = tot[32+t] / NRED - mean*mean;
        const float rstd = rsqrtf(var + 1e-5f);
        const float scale = gamma[t] * rstd;
        sc[t]    = scale;
        sc[32+t] = fmaf(-mean, scale, beta[t]);
    }
}

// stage 3: in-place affine normalize of d_out
__global__ __launch_bounds__(256) void k3_norm(float* __restrict__ out,
                                               const float* __restrict__ sc)
{
    __shared__ float s[64];
    if (threadIdx.x < 64) s[threadIdx.x] = sc[threadIdx.x];
    __syncthreads();
    const int total4 = 2*32*CHS/4;
    const int Q = CHS/4;
    for (int i = blockIdx.x*256 + threadIdx.x; i < total4; i += gridDim.x*256) {
        float4 v = ((const float4*)out)[i];
        const int c = (i / Q) & 31;
        const float scale = s[c], shift = s[32+c];
        v.x = fmaf(v.x, scale, shift);
        v.y = fmaf(v.y, scale, shift);
        v.z = fmaf(v.z, scale, shift);
        v.w = fmaf(v.w, scale, shift);
        ((float4*)out)[i] = v;
    }
}

extern "C" void kernel_launch(void* const* d_in, const int* in_sizes, int n_in,
                              void* d_out, int out_size, void* d_ws, size_t ws_size,
                              hipStream_t stream) {
    const float* x        = (const float*)d_in[0];
    const float* spacings = (const float*)d_in[1];
    const float* theta_w  = (const float*)d_in[2];
    const float* theta_b  = (const float*)d_in[3];
    const float* phi_w    = (const float*)d_in[4];
    const float* phi_b    = (const float*)d_in[5];
    const float* g_w      = (const float*)d_in[6];
    const float* g_b      = (const float*)d_in[7];
    const float* Ww       = (const float*)d_in[8];
    const float* Wb       = (const float*)d_in[9];
    const float* gamma    = (const float*)d_in[10];
    const float* beta     = (const float*)d_in[11];
    float* out   = (float*)d_out;
    char*  frags = (char*)d_ws;                         // WSFRAG bytes
    float* part  = (float*)((char*)d_ws + WSFRAG);      // ROWS*256 floats
    float* part2 = part + (size_t)ROWS*256;             // 256*64 floats
    float* sc    = part2 + 256*64;                      // 64 floats

    hipLaunchKernelGGL(k0_frag, dim3(1), dim3(256), 0, stream, theta_w, phi_w, Ww, frags);
    hipLaunchKernelGGL(k1_row, dim3(ROWS/2), dim3(128), 0, stream,
                       x, spacings, theta_b, phi_b, g_w, g_b, Wb, frags, out, part);
    hipLaunchKernelGGL(k2a, dim3(256), dim3(256), 0, stream, part, part2);
    hipLaunchKernelGGL(k2b, dim3(1), dim3(256), 0, stream, part2, gamma, beta, sc);
    hipLaunchKernelGGL(k3_norm, dim3(4096), dim3(256), 0, stream, out, sc);
}

// Round 18
// 171.774 us; speedup vs baseline: 1.2097x; 1.2097x over previous
//
#include <hip/hip_runtime.h>
#include <stdint.h>

#define CHS 589824           // W*H*Z
#define ROWS 18432           // B*W*H
#define WHn 9216             // W*H
#define NRED 1179648.0f      // B*W*H*Z
#define LOG2E 1.4426950408889634f

typedef short s16x8 __attribute__((ext_vector_type(8)));
typedef float f32x4v __attribute__((ext_vector_type(4)));

#define MFMA16 __builtin_amdgcn_mfma_f32_16x16x32_bf16

// ws layout (bytes): [0,10240) weight frags ; then part (ROWS*256 f32) / part2 / sc
#define WSFRAG 10240

// LDS (block = 1 row, 128 threads = 2 waves; each wave owns 2 z-tiles)
#define OXH 0        // X bf16 [z=64][ hi c:32 (64B) | lo c:32 (64B) ] stride 136 (8704)
#define OP  8704     // P_hi bf16 [y=64][p:36] stride 72 (4608)
#define OG  13312    // G bf16 [c=32][pg:68] stride 136 (4352)
#define LDSZ 17664   // 9 blocks/CU (LDS-capped), 18 waves/CU

static __device__ __forceinline__ uint16_t bfh(float v) {
    union { __bf16 h; uint16_t u; } c; c.h = (__bf16)v; return c.u;
}
static __device__ __forceinline__ float bf2f(uint16_t u) {
    union { uint32_t x; float f; } c; c.x = (uint32_t)u << 16; return c.f;
}
static __device__ __forceinline__ uint32_t pk2u(uint16_t a, uint16_t b) {
    return (uint32_t)a | ((uint32_t)b << 16);
}
static __device__ __forceinline__ uint32_t pkbf(float a, float b) {
    return pk2u(bfh(a), bfh(b));
}
static __device__ __forceinline__ float ex2(float x) {
    float r;
    asm("v_exp_f32 %0, %1" : "=v"(r) : "v"(x));
    return r;
}
// 16B from 8B-aligned LDS as two b64s
static __device__ __forceinline__ s16x8 rd8(const char* p) {
    union { uint64_t q[2]; s16x8 s; } v;
    v.q[0] = *(const uint64_t*)p;
    v.q[1] = *(const uint64_t*)(p + 8);
    return v.s;
}

// identity-k hi+lo A-frags of row-major [32][32] f32 weights, optional pre-scale
static __device__ __forceinline__ void wfrag2(const float* __restrict__ Wp, int mt, int l15, int kb,
                                              float sc, s16x8& hi, s16x8& lo) {
    const float* p = Wp + (l15 + 16*mt)*32 + 8*kb;
    const float4 f0 = *(const float4*)p;
    const float4 f1 = *(const float4*)(p + 4);
    float f[8] = {f0.x*sc, f0.y*sc, f0.z*sc, f0.w*sc, f1.x*sc, f1.y*sc, f1.z*sc, f1.w*sc};
    union { uint32_t u[4]; s16x8 v; } rh, rl;
    #pragma unroll
    for (int i = 0; i < 4; ++i) {
        const uint16_t h0 = bfh(f[2*i]), h1 = bfh(f[2*i+1]);
        rh.u[i] = pk2u(h0, h1);
        rl.u[i] = pk2u(bfh(f[2*i] - bf2f(h0)), bfh(f[2*i+1] - bf2f(h1)));
    }
    hi = rh.v; lo = rl.v;
}
// c-permuted A-frag for W (slot j <-> c = 16*(j>>2) + 4*kb + (j&3))
static __device__ __forceinline__ s16x8 wfragW(const float* __restrict__ Wp, int mt, int l15, int kb) {
    const float* p = Wp + (l15 + 16*mt)*32;
    const float4 f0 = *(const float4*)(p + 4*kb);
    const float4 f1 = *(const float4*)(p + 16 + 4*kb);
    union { uint32_t u[4]; s16x8 v; } r;
    r.u[0] = pkbf(f0.x, f0.y); r.u[1] = pkbf(f0.z, f0.w);
    r.u[2] = pkbf(f1.x, f1.y); r.u[3] = pkbf(f1.z, f1.w);
    return r.v;
}

// k0: one block, precompute weight fragments into ws (theta scaled by LOG2E)
__global__ __launch_bounds__(256) void k0_frag(
    const float* __restrict__ theta_w, const float* __restrict__ phi_w,
    const float* __restrict__ Ww, char* __restrict__ ws)
{
    const int tid = threadIdx.x;
    const int m = tid >> 7;            // 0 = theta, 1 = phi
    const int r = tid & 127;
    const int mt = r >> 6, l = r & 63;
    s16x8 hi, lo;
    wfrag2(m ? phi_w : theta_w, mt, l & 15, l >> 4, m ? 1.0f : LOG2E, hi, lo);
    *(s16x8*)(ws + m*4096 + (mt*64 + l)*16)        = hi;
    *(s16x8*)(ws + m*4096 + 2048 + (mt*64 + l)*16) = lo;
    if (tid < 128) {
        const int mtw = tid >> 6, lw = tid & 63;
        *(s16x8*)(ws + 8192 + (mtw*64 + lw)*16) = wfragW(Ww, mtw, lw & 15, lw >> 4);
    }
}

__global__ __launch_bounds__(128, 4) void k1_row(
    const float* __restrict__ x, const float* __restrict__ spacings,
    const float* __restrict__ theta_b, const float* __restrict__ phi_b,
    const float* __restrict__ g_w, const float* __restrict__ g_b,
    const float* __restrict__ Wb, const char* __restrict__ frags,
    float* __restrict__ out, float* __restrict__ part)
{
    __shared__ __align__(16) char lds[LDSZ];
    const int t = threadIdx.x;
    const int wv = t >> 6, l = t & 63;       // wv in {0,1}
    const int l15 = l & 15, kb = l >> 4;
    const int row = blockIdx.x;
    const int b = row / WHn, wh = row - b*WHn;
    const long base = (long)b*32*CHS + (long)wh*64;

    // ===== phase 0: issue all 16 loads (c = 16wv..16wv+15 at z=l), then process =====
    float xv[16];
    {
        const float* xp = x + base;
        #pragma unroll
        for (int j = 0; j < 16; ++j) xv[j] = xp[(long)(16*wv + j)*CHS + l];
    }
    {
        #pragma unroll
        for (int j = 0; j < 8; ++j) {
            const int c0 = 16*wv + 2*j;
            const uint16_t h0 = bfh(xv[2*j]), h1 = bfh(xv[2*j+1]);
            *(uint32_t*)(lds + OXH + l*136 + c0*2)      = pk2u(h0, h1);
            *(uint32_t*)(lds + OXH + l*136 + 64 + c0*2) =
                pk2u(bfh(xv[2*j] - bf2f(h0)), bfh(xv[2*j+1] - bf2f(h1)));
        }
        const int pG = 32*(l >> 5) + 8*((l >> 2) & 3) + 4*((l >> 4) & 1) + (l & 3);
        #pragma unroll
        for (int j = 0; j < 16; ++j) {
            const int c = 16*wv + j;
            float xm = __shfl_up(xv[j], 1);    if (l == 0)  xm = 0.f;
            float xp2 = __shfl_down(xv[j], 1); if (l == 63) xp2 = 0.f;
            const float g = g_w[3*c]*xm + g_w[3*c+1]*xv[j] + g_w[3*c+2]*xp2 + g_b[c];
            *(uint16_t*)(lds + OG + c*136 + 2*pG) = bfh(g);
        }
    }
    __syncthreads();   // B1 (2-wave scope)

    // ===== phase 1: own 2 z-tiles: T kept in regs, P (hi) -> LDS =====
    s16x8 bth[2], btl[2];
    {
        s16x8 bxh[2], bxl[2];
        #pragma unroll
        for (int nt = 0; nt < 2; ++nt) {
            const int zr = 32*wv + 16*nt + l15;
            bxh[nt] = rd8(lds + OXH + zr*136 + 16*kb);
            bxl[nt] = rd8(lds + OXH + zr*136 + 64 + 16*kb);
        }
        // ---- theta pass ----
        {
            const s16x8 t0h = *(const s16x8*)(frags + l*16);
            const s16x8 t1h = *(const s16x8*)(frags + 1024 + l*16);
            const s16x8 t0l = *(const s16x8*)(frags + 2048 + l*16);
            const s16x8 t1l = *(const s16x8*)(frags + 3072 + l*16);
            const float4 b0 = *(const float4*)(theta_b + 4*kb);
            const float4 b1 = *(const float4*)(theta_b + 16 + 4*kb);
            #pragma unroll
            for (int nt = 0; nt < 2; ++nt) {
                f32x4v T0; T0[0]=b0.x*LOG2E; T0[1]=b0.y*LOG2E; T0[2]=b0.z*LOG2E; T0[3]=b0.w*LOG2E;
                f32x4v T1; T1[0]=b1.x*LOG2E; T1[1]=b1.y*LOG2E; T1[2]=b1.z*LOG2E; T1[3]=b1.w*LOG2E;
                T0 = MFMA16(t0h, bxh[nt], T0, 0, 0, 0);
                T0 = MFMA16(t0h, bxl[nt], T0, 0, 0, 0);
                T0 = MFMA16(t0l, bxh[nt], T0, 0, 0, 0);
                T1 = MFMA16(t1h, bxh[nt], T1, 0, 0, 0);
                T1 = MFMA16(t1h, bxl[nt], T1, 0, 0, 0);
                T1 = MFMA16(t1l, bxh[nt], T1, 0, 0, 0);
                uint16_t h[8];
                #pragma unroll
                for (int r = 0; r < 4; ++r) { h[r] = bfh(T0[r]); h[4+r] = bfh(T1[r]); }
                union { uint32_t u[4]; s16x8 s; } H, L2;
                H.u[0] = pk2u(h[0], h[1]); H.u[1] = pk2u(h[2], h[3]);
                H.u[2] = pk2u(h[4], h[5]); H.u[3] = pk2u(h[6], h[7]);
                L2.u[0] = pkbf(T0[0]-bf2f(h[0]), T0[1]-bf2f(h[1]));
                L2.u[1] = pkbf(T0[2]-bf2f(h[2]), T0[3]-bf2f(h[3]));
                L2.u[2] = pkbf(T1[0]-bf2f(h[4]), T1[1]-bf2f(h[5]));
                L2.u[3] = pkbf(T1[2]-bf2f(h[6]), T1[3]-bf2f(h[7]));
                bth[nt] = H.s; btl[nt] = L2.s;
            }
        }
        // ---- phi pass ----
        {
            const s16x8 p0h = *(const s16x8*)(frags + 4096 + l*16);
            const s16x8 p1h = *(const s16x8*)(frags + 4096 + 1024 + l*16);
            const s16x8 p0l = *(const s16x8*)(frags + 4096 + 2048 + l*16);
            const s16x8 p1l = *(const s16x8*)(frags + 4096 + 3072 + l*16);
            const float4 c0 = *(const float4*)(phi_b + 4*kb);
            const float4 c1 = *(const float4*)(phi_b + 16 + 4*kb);
            #pragma unroll
            for (int nt = 0; nt < 2; ++nt) {
                const int zr = 32*wv + 16*nt + l15;
                f32x4v P0; P0[0]=c0.x; P0[1]=c0.y; P0[2]=c0.z; P0[3]=c0.w;
                f32x4v P1; P1[0]=c1.x; P1[1]=c1.y; P1[2]=c1.z; P1[3]=c1.w;
                P0 = MFMA16(p0h, bxh[nt], P0, 0, 0, 0);
                P0 = MFMA16(p0h, bxl[nt], P0, 0, 0, 0);
                P0 = MFMA16(p0l, bxh[nt], P0, 0, 0, 0);
                P1 = MFMA16(p1h, bxh[nt], P1, 0, 0, 0);
                P1 = MFMA16(p1h, bxl[nt], P1, 0, 0, 0);
                P1 = MFMA16(p1l, bxh[nt], P1, 0, 0, 0);
                union { uint32_t u[2]; uint64_t q; } w;
                w.u[0] = pkbf(P0[0], P0[1]); w.u[1] = pkbf(P0[2], P0[3]);
                *(uint64_t*)(lds + OP + zr*72 + 16*kb) = w.q;
                w.u[0] = pkbf(P1[0], P1[1]); w.u[1] = pkbf(P1[2], P1[3]);
                *(uint64_t*)(lds + OP + zr*72 + 16*kb + 8) = w.q;
            }
        }
    }
    __syncthreads();   // B2 (P complete)

    // ===== phase 2a: F' = P^T * (T_hi + T_lo), both z-tiles =====
    f32x4v Fq[2][4];
    __builtin_amdgcn_s_setprio(1);
    #pragma unroll
    for (int yt = 0; yt < 4; ++yt) {
        const s16x8 pah = rd8(lds + OP + (16*yt + l15)*72 + 16*kb);
        #pragma unroll
        for (int nt = 0; nt < 2; ++nt) {
            f32x4v zz; zz[0]=0.f; zz[1]=0.f; zz[2]=0.f; zz[3]=0.f;
            zz = MFMA16(pah, bth[nt], zz, 0, 0, 0);
            zz = MFMA16(pah, btl[nt], zz, 0, 0, 0);
            Fq[nt][yt] = zz;
        }
    }
    __builtin_amdgcn_s_setprio(0);

    // ===== phase 2b: softmax via exp2 (unnormalized), pack A' frags, both tiles =====
    s16x8 apk[2][2];
    float inv[2];
    #pragma unroll
    for (int nt = 0; nt < 2; ++nt) {
        float mx = -3.4e38f;
        #pragma unroll
        for (int yt = 0; yt < 4; ++yt)
            #pragma unroll
            for (int r = 0; r < 4; ++r) mx = fmaxf(mx, Fq[nt][yt][r]);
        mx = fmaxf(mx, __shfl_xor(mx, 16));
        mx = fmaxf(mx, __shfl_xor(mx, 32));
        float p[4][4]; float sum = 0.f;
        #pragma unroll
        for (int yt = 0; yt < 4; ++yt)
            #pragma unroll
            for (int r = 0; r < 4; ++r) { p[yt][r] = ex2(Fq[nt][yt][r] - mx); sum += p[yt][r]; }
        sum += __shfl_xor(sum, 16);
        sum += __shfl_xor(sum, 32);
        inv[nt] = 1.0f / sum;
        #pragma unroll
        for (int ks = 0; ks < 2; ++ks) {
            union { uint32_t u[4]; s16x8 s; } A;
            A.u[0] = pkbf(p[2*ks][0],   p[2*ks][1]);
            A.u[1] = pkbf(p[2*ks][2],   p[2*ks][3]);
            A.u[2] = pkbf(p[2*ks+1][0], p[2*ks+1][1]);
            A.u[3] = pkbf(p[2*ks+1][2], p[2*ks+1][3]);
            apk[nt][ks] = A.s;
        }
    }

    // ===== phase 3: Y = G*A'^T, rescale+residual(+mask), R frag, both tiles =====
    const bool msk = spacings[b*3 + 2] <= 1.5f;
    s16x8 brf[2];
    #pragma unroll
    for (int nt = 0; nt < 2; ++nt) {
        const int zr = 32*wv + 16*nt + l15;
        f32x4v Yq[2];
        #pragma unroll
        for (int r = 0; r < 4; ++r) { Yq[0][r] = 0.f; Yq[1][r] = 0.f; }
        __builtin_amdgcn_s_setprio(1);
        #pragma unroll
        for (int ks = 0; ks < 2; ++ks) {
            #pragma unroll
            for (int mt = 0; mt < 2; ++mt) {
                const s16x8 gA = rd8(lds + OG + (16*mt + l15)*136 + 64*ks + 16*kb);
                Yq[mt] = MFMA16(gA, apk[nt][ks], Yq[mt], 0, 0, 0);
            }
        }
        __builtin_amdgcn_s_setprio(0);
        union { uint32_t u[4]; s16x8 s; } R;
        #pragma unroll
        for (int mt = 0; mt < 2; ++mt) {
            const uint64_t xh = *(const uint64_t*)(lds + OXH + zr*136 + (16*mt + 4*kb)*2);
            float rv[4];
            #pragma unroll
            for (int r = 0; r < 4; ++r) {
                const float xr = bf2f((uint16_t)(xh >> (16*r)));
                rv[r] = msk ? fmaf(Yq[mt][r], inv[nt], xr) : xr;
            }
            R.u[2*mt]   = pkbf(rv[0], rv[1]);
            R.u[2*mt+1] = pkbf(rv[2], rv[3]);
        }
        brf[nt] = R.s;
    }
    // no barrier: phase 4 touches no LDS

    // ===== phase 4: O = W*R + wb -> global; BN partials -> part, both tiles =====
    {
        const s16x8 aW0 = *(const s16x8*)(frags + 8192 + l*16);
        const s16x8 aW1 = *(const s16x8*)(frags + 8192 + (64 + l)*16);
        const float4 wb0 = *(const float4*)(Wb + 4*kb);
        const float4 wb1 = *(const float4*)(Wb + 16 + 4*kb);
        #pragma unroll
        for (int nt = 0; nt < 2; ++nt) {
            const int zr = 32*wv + 16*nt + l15;
            f32x4v accs[2];
            f32x4v a0; a0[0]=wb0.x; a0[1]=wb0.y; a0[2]=wb0.z; a0[3]=wb0.w;
            f32x4v a1; a1[0]=wb1.x; a1[1]=wb1.y; a1[2]=wb1.z; a1[3]=wb1.w;
            __builtin_amdgcn_s_setprio(1);
            accs[0] = MFMA16(aW0, brf[nt], a0, 0, 0, 0);
            accs[1] = MFMA16(aW1, brf[nt], a1, 0, 0, 0);
            __builtin_amdgcn_s_setprio(0);
            float* op = out + base + zr;
            #pragma unroll
            for (int mt = 0; mt < 2; ++mt)
                #pragma unroll
                for (int r = 0; r < 4; ++r)
                    op[(long)(16*mt + 4*kb + r)*CHS] = accs[mt][r];
            const int sr = row*4 + 2*wv + nt;
            float bs[8];
            #pragma unroll
            for (int mt = 0; mt < 2; ++mt)
                #pragma unroll
                for (int r = 0; r < 4; ++r) bs[4*mt+r] = accs[mt][r];
            #pragma unroll
            for (int off = 1; off < 16; off <<= 1)
                #pragma unroll
                for (int i = 0; i < 8; ++i) bs[i] += __shfl_xor(bs[i], off);
            if (l15 == 0) {
                #pragma unroll
                for (int mt = 0; mt < 2; ++mt)
                    #pragma unroll
                    for (int r = 0; r < 4; ++r)
                        part[sr*64 + 16*mt + 4*kb + r] = bs[4*mt+r];
            }
            #pragma unroll
            for (int mt = 0; mt < 2; ++mt)
                #pragma unroll
                for (int r = 0; r < 4; ++r) { const float v = accs[mt][r]; bs[4*mt+r] = v*v; }
            #pragma unroll
            for (int off = 1; off < 16; off <<= 1)
                #pragma unroll
                for (int i = 0; i < 8; ++i) bs[i] += __shfl_xor(bs[i], off);
            if (l15 == 0) {
                #pragma unroll
                for (int mt = 0; mt < 2; ++mt)
                    #pragma unroll
                    for (int r = 0; r < 4; ++r)
                        part[sr*64 + 32 + 16*mt + 4*kb + r] = bs[4*mt+r];
            }
        }
    }
}

// stage 2a: 256 blocks, each reduces 288 sub-rows (= 72 rows x 4 z-tiles)
__global__ __launch_bounds__(256) void k2a(const float* __restrict__ part,
                                           float* __restrict__ part2)
{
    __shared__ float red[4][64];
    const int t = threadIdx.x, lane = t & 63, grp = t >> 6;
    const int p = blockIdx.x;
    float s = 0.f;
    for (int k = 0; k < 72; ++k) s += part[(p*288 + grp + 4*k)*64 + lane];
    red[grp][lane] = s;
    __syncthreads();
    if (t < 64) part2[p*64 + t] = red[0][t] + red[1][t] + red[2][t] + red[3][t];
}

// stage 2b: final reduce + BN scale/shift
__global__ __launch_bounds__(256) void k2b(const float* __restrict__ part2,
    const float* __restrict__ gamma, const float* __restrict__ beta,
    float* __restrict__ sc)
{
    __shared__ float red[4][64];
    __shared__ float tot[64];
    const int t = threadIdx.x, lane = t & 63, grp = t >> 6;
    float s = 0.f;
    for (int k = 0; k < 64; ++k) s += part2[(grp + 4*k)*64 + lane];
    red[grp][lane] = s;
    __syncthreads();
    if (t < 64) tot[t] = red[0][t] + red[1][t] + red[2][t] + red[3][t];
    __syncthreads();
    if (t < 32) {
        const float mean = tot[t] / NRED;
        const float var  = tot[32+t] / NRED - mean*mean;
        const float rstd = rsqrtf(var + 1e-5f);
        const float scale = gamma[t] * rstd;
        sc[t]    = scale;
        sc[32+t] = fmaf(-mean, scale, beta[t]);
    }
}

// stage 3: in-place affine normalize of d_out
__global__ __launch_bounds__(256) void k3_norm(float* __restrict__ out,
                                               const float* __restrict__ sc)
{
    __shared__ float s[64];
    if (threadIdx.x < 64) s[threadIdx.x] = sc[threadIdx.x];
    __syncthreads();
    const int total4 = 2*32*CHS/4;
    const int Q = CHS/4;
    for (int i = blockIdx.x*256 + threadIdx.x; i < total4; i += gridDim.x*256) {
        float4 v = ((const float4*)out)[i];
        const int c = (i / Q) & 31;
        const float scale = s[c], shift = s[32+c];
        v.x = fmaf(v.x, scale, shift);
        v.y = fmaf(v.y, scale, shift);
        v.z = fmaf(v.z, scale, shift);
        v.w = fmaf(v.w, scale, shift);
        ((float4*)out)[i] = v;
    }
}

extern "C" void kernel_launch(void* const* d_in, const int* in_sizes, int n_in,
                              void* d_out, int out_size, void* d_ws, size_t ws_size,
                              hipStream_t stream) {
    const float* x        = (const float*)d_in[0];
    const float* spacings = (const float*)d_in[1];
    const float* theta_w  = (const float*)d_in[2];
    const float* theta_b  = (const float*)d_in[3];
    const float* phi_w    = (const float*)d_in[4];
    const float* phi_b    = (const float*)d_in[5];
    const float* g_w      = (const float*)d_in[6];
    const float* g_b      = (const float*)d_in[7];
    const float* Ww       = (const float*)d_in[8];
    const float* Wb       = (const float*)d_in[9];
    const float* gamma    = (const float*)d_in[10];
    const float* beta     = (const float*)d_in[11];
    float* out   = (float*)d_out;
    char*  frags = (char*)d_ws;                         // WSFRAG bytes
    float* part  = (float*)((char*)d_ws + WSFRAG);      // ROWS*256 floats
    float* part2 = part + (size_t)ROWS*256;             // 256*64 floats
    float* sc    = part2 + 256*64;                      // 64 floats

    hipLaunchKernelGGL(k0_frag, dim3(1), dim3(256), 0, stream, theta_w, phi_w, Ww, frags);
    hipLaunchKernelGGL(k1_row, dim3(ROWS), dim3(128), 0, stream,
                       x, spacings, theta_b, phi_b, g_w, g_b, Wb, frags, out, part);
    hipLaunchKernelGGL(k2a, dim3(256), dim3(256), 0, stream, part, part2);
    hipLaunchKernelGGL(k2b, dim3(1), dim3(256), 0, stream, part2, gamma, beta, sc);
    hipLaunchKernelGGL(k3_norm, dim3(4096), dim3(256), 0, stream, out, sc);
}

// Round 19
// 162.803 us; speedup vs baseline: 1.2763x; 1.0551x over previous
//
#include <hip/hip_runtime.h>
#include <stdint.h>

#define CHS 589824           // W*H*Z
#define ROWS 18432           // B*W*H
#define WHn 9216             // W*H
#define NRED 1179648.0f      // B*W*H*Z
#define LOG2E 1.4426950408889634f

typedef short s16x8 __attribute__((ext_vector_type(8)));
typedef float f32x4v __attribute__((ext_vector_type(4)));

#define MFMA16 __builtin_amdgcn_mfma_f32_16x16x32_bf16

// ws layout (bytes): [0,10240) weight frags ; part ROWS*256 f32 ; part2 ; sc ; [obf]
#define WSFRAG 10240

// LDS (block = 1 row, 128 threads = 2 waves; each wave owns 2 z-tiles)
#define OXH 0        // X bf16 [z=64][ hi c:32 (64B) | lo c:32 (64B) ] stride 136 (8704)
#define OP  8704     // P_hi bf16 [y=64][p:36] stride 72 (4608)
#define OG  13312    // G bf16 [c=32][pg:68] stride 136 (4352)
#define LDSZ 17664   // 9 blocks/CU (LDS-capped), 18 waves/CU

static __device__ __forceinline__ uint16_t bfh(float v) {
    union { __bf16 h; uint16_t u; } c; c.h = (__bf16)v; return c.u;
}
static __device__ __forceinline__ float bf2f(uint16_t u) {
    union { uint32_t x; float f; } c; c.x = (uint32_t)u << 16; return c.f;
}
static __device__ __forceinline__ uint32_t pk2u(uint16_t a, uint16_t b) {
    return (uint32_t)a | ((uint32_t)b << 16);
}
static __device__ __forceinline__ uint32_t pkbf(float a, float b) {
    return pk2u(bfh(a), bfh(b));
}
static __device__ __forceinline__ float ex2(float x) {
    float r;
    asm("v_exp_f32 %0, %1" : "=v"(r) : "v"(x));
    return r;
}
// 16B from 8B-aligned LDS as two b64s
static __device__ __forceinline__ s16x8 rd8(const char* p) {
    union { uint64_t q[2]; s16x8 s; } v;
    v.q[0] = *(const uint64_t*)p;
    v.q[1] = *(const uint64_t*)(p + 8);
    return v.s;
}

// identity-k hi+lo A-frags of row-major [32][32] f32 weights, optional pre-scale
static __device__ __forceinline__ void wfrag2(const float* __restrict__ Wp, int mt, int l15, int kb,
                                              float sc, s16x8& hi, s16x8& lo) {
    const float* p = Wp + (l15 + 16*mt)*32 + 8*kb;
    const float4 f0 = *(const float4*)p;
    const float4 f1 = *(const float4*)(p + 4);
    float f[8] = {f0.x*sc, f0.y*sc, f0.z*sc, f0.w*sc, f1.x*sc, f1.y*sc, f1.z*sc, f1.w*sc};
    union { uint32_t u[4]; s16x8 v; } rh, rl;
    #pragma unroll
    for (int i = 0; i < 4; ++i) {
        const uint16_t h0 = bfh(f[2*i]), h1 = bfh(f[2*i+1]);
        rh.u[i] = pk2u(h0, h1);
        rl.u[i] = pk2u(bfh(f[2*i] - bf2f(h0)), bfh(f[2*i+1] - bf2f(h1)));
    }
    hi = rh.v; lo = rl.v;
}
// c-permuted A-frag for W (slot j <-> c = 16*(j>>2) + 4*kb + (j&3))
static __device__ __forceinline__ s16x8 wfragW(const float* __restrict__ Wp, int mt, int l15, int kb) {
    const float* p = Wp + (l15 + 16*mt)*32;
    const float4 f0 = *(const float4*)(p + 4*kb);
    const float4 f1 = *(const float4*)(p + 16 + 4*kb);
    union { uint32_t u[4]; s16x8 v; } r;
    r.u[0] = pkbf(f0.x, f0.y); r.u[1] = pkbf(f0.z, f0.w);
    r.u[2] = pkbf(f1.x, f1.y); r.u[3] = pkbf(f1.z, f1.w);
    return r.v;
}

// k0: one block, precompute weight fragments into ws (theta scaled by LOG2E)
__global__ __launch_bounds__(256) void k0_frag(
    const float* __restrict__ theta_w, const float* __restrict__ phi_w,
    const float* __restrict__ Ww, char* __restrict__ ws)
{
    const int tid = threadIdx.x;
    const int m = tid >> 7;            // 0 = theta, 1 = phi
    const int r = tid & 127;
    const int mt = r >> 6, l = r & 63;
    s16x8 hi, lo;
    wfrag2(m ? phi_w : theta_w, mt, l & 15, l >> 4, m ? 1.0f : LOG2E, hi, lo);
    *(s16x8*)(ws + m*4096 + (mt*64 + l)*16)        = hi;
    *(s16x8*)(ws + m*4096 + 2048 + (mt*64 + l)*16) = lo;
    if (tid < 128) {
        const int mtw = tid >> 6, lw = tid & 63;
        *(s16x8*)(ws + 8192 + (mtw*64 + lw)*16) = wfragW(Ww, mtw, lw & 15, lw >> 4);
    }
}

__global__ __launch_bounds__(128, 4) void k1_row(
    const float* __restrict__ x, const float* __restrict__ spacings,
    const float* __restrict__ theta_b, const float* __restrict__ phi_b,
    const float* __restrict__ g_w, const float* __restrict__ g_b,
    const float* __restrict__ Wb, const char* __restrict__ frags,
    float* __restrict__ out, unsigned short* __restrict__ obf, int use16,
    float* __restrict__ part)
{
    __shared__ __align__(16) char lds[LDSZ];
    const int t = threadIdx.x;
    const int wv = t >> 6, l = t & 63;       // wv in {0,1}
    const int l15 = l & 15, kb = l >> 4;
    const int row = blockIdx.x;
    const int b = row / WHn, wh = row - b*WHn;
    const long base = (long)b*32*CHS + (long)wh*64;

    // ===== phase 0: issue all 16 loads (c = 16wv..16wv+15 at z=l), then process =====
    float xv[16];
    {
        const float* xp = x + base;
        #pragma unroll
        for (int j = 0; j < 16; ++j) xv[j] = xp[(long)(16*wv + j)*CHS + l];
    }
    {
        #pragma unroll
        for (int j = 0; j < 8; ++j) {
            const int c0 = 16*wv + 2*j;
            const uint16_t h0 = bfh(xv[2*j]), h1 = bfh(xv[2*j+1]);
            *(uint32_t*)(lds + OXH + l*136 + c0*2)      = pk2u(h0, h1);
            *(uint32_t*)(lds + OXH + l*136 + 64 + c0*2) =
                pk2u(bfh(xv[2*j] - bf2f(h0)), bfh(xv[2*j+1] - bf2f(h1)));
        }
        const int pG = 32*(l >> 5) + 8*((l >> 2) & 3) + 4*((l >> 4) & 1) + (l & 3);
        #pragma unroll
        for (int j = 0; j < 16; ++j) {
            const int c = 16*wv + j;
            float xm = __shfl_up(xv[j], 1);    if (l == 0)  xm = 0.f;
            float xp2 = __shfl_down(xv[j], 1); if (l == 63) xp2 = 0.f;
            const float g = g_w[3*c]*xm + g_w[3*c+1]*xv[j] + g_w[3*c+2]*xp2 + g_b[c];
            *(uint16_t*)(lds + OG + c*136 + 2*pG) = bfh(g);
        }
    }
    __syncthreads();   // B1 (2-wave scope)

    // ===== phase 1: own 2 z-tiles: T kept in regs, P (hi) -> LDS =====
    s16x8 bth[2], btl[2];
    {
        s16x8 bxh[2], bxl[2];
        #pragma unroll
        for (int nt = 0; nt < 2; ++nt) {
            const int zr = 32*wv + 16*nt + l15;
            bxh[nt] = rd8(lds + OXH + zr*136 + 16*kb);
            bxl[nt] = rd8(lds + OXH + zr*136 + 64 + 16*kb);
        }
        // ---- theta pass ----
        {
            const s16x8 t0h = *(const s16x8*)(frags + l*16);
            const s16x8 t1h = *(const s16x8*)(frags + 1024 + l*16);
            const s16x8 t0l = *(const s16x8*)(frags + 2048 + l*16);
            const s16x8 t1l = *(const s16x8*)(frags + 3072 + l*16);
            const float4 b0 = *(const float4*)(theta_b + 4*kb);
            const float4 b1 = *(const float4*)(theta_b + 16 + 4*kb);
            #pragma unroll
            for (int nt = 0; nt < 2; ++nt) {
                f32x4v T0; T0[0]=b0.x*LOG2E; T0[1]=b0.y*LOG2E; T0[2]=b0.z*LOG2E; T0[3]=b0.w*LOG2E;
                f32x4v T1; T1[0]=b1.x*LOG2E; T1[1]=b1.y*LOG2E; T1[2]=b1.z*LOG2E; T1[3]=b1.w*LOG2E;
                T0 = MFMA16(t0h, bxh[nt], T0, 0, 0, 0);
                T0 = MFMA16(t0h, bxl[nt], T0, 0, 0, 0);
                T0 = MFMA16(t0l, bxh[nt], T0, 0, 0, 0);
                T1 = MFMA16(t1h, bxh[nt], T1, 0, 0, 0);
                T1 = MFMA16(t1h, bxl[nt], T1, 0, 0, 0);
                T1 = MFMA16(t1l, bxh[nt], T1, 0, 0, 0);
                uint16_t h[8];
                #pragma unroll
                for (int r = 0; r < 4; ++r) { h[r] = bfh(T0[r]); h[4+r] = bfh(T1[r]); }
                union { uint32_t u[4]; s16x8 s; } H, L2;
                H.u[0] = pk2u(h[0], h[1]); H.u[1] = pk2u(h[2], h[3]);
                H.u[2] = pk2u(h[4], h[5]); H.u[3] = pk2u(h[6], h[7]);
                L2.u[0] = pkbf(T0[0]-bf2f(h[0]), T0[1]-bf2f(h[1]));
                L2.u[1] = pkbf(T0[2]-bf2f(h[2]), T0[3]-bf2f(h[3]));
                L2.u[2] = pkbf(T1[0]-bf2f(h[4]), T1[1]-bf2f(h[5]));
                L2.u[3] = pkbf(T1[2]-bf2f(h[6]), T1[3]-bf2f(h[7]));
                bth[nt] = H.s; btl[nt] = L2.s;
            }
        }
        // ---- phi pass ----
        {
            const s16x8 p0h = *(const s16x8*)(frags + 4096 + l*16);
            const s16x8 p1h = *(const s16x8*)(frags + 4096 + 1024 + l*16);
            const s16x8 p0l = *(const s16x8*)(frags + 4096 + 2048 + l*16);
            const s16x8 p1l = *(const s16x8*)(frags + 4096 + 3072 + l*16);
            const float4 c0 = *(const float4*)(phi_b + 4*kb);
            const float4 c1 = *(const float4*)(phi_b + 16 + 4*kb);
            #pragma unroll
            for (int nt = 0; nt < 2; ++nt) {
                const int zr = 32*wv + 16*nt + l15;
                f32x4v P0; P0[0]=c0.x; P0[1]=c0.y; P0[2]=c0.z; P0[3]=c0.w;
                f32x4v P1; P1[0]=c1.x; P1[1]=c1.y; P1[2]=c1.z; P1[3]=c1.w;
                P0 = MFMA16(p0h, bxh[nt], P0, 0, 0, 0);
                P0 = MFMA16(p0h, bxl[nt], P0, 0, 0, 0);
                P0 = MFMA16(p0l, bxh[nt], P0, 0, 0, 0);
                P1 = MFMA16(p1h, bxh[nt], P1, 0, 0, 0);
                P1 = MFMA16(p1h, bxl[nt], P1, 0, 0, 0);
                P1 = MFMA16(p1l, bxh[nt], P1, 0, 0, 0);
                union { uint32_t u[2]; uint64_t q; } w;
                w.u[0] = pkbf(P0[0], P0[1]); w.u[1] = pkbf(P0[2], P0[3]);
                *(uint64_t*)(lds + OP + zr*72 + 16*kb) = w.q;
                w.u[0] = pkbf(P1[0], P1[1]); w.u[1] = pkbf(P1[2], P1[3]);
                *(uint64_t*)(lds + OP + zr*72 + 16*kb + 8) = w.q;
            }
        }
    }
    __syncthreads();   // B2 (P complete)

    // ===== phase 2a: F' = P^T * (T_hi + T_lo), both z-tiles =====
    f32x4v Fq[2][4];
    __builtin_amdgcn_s_setprio(1);
    #pragma unroll
    for (int yt = 0; yt < 4; ++yt) {
        const s16x8 pah = rd8(lds + OP + (16*yt + l15)*72 + 16*kb);
        #pragma unroll
        for (int nt = 0; nt < 2; ++nt) {
            f32x4v zz; zz[0]=0.f; zz[1]=0.f; zz[2]=0.f; zz[3]=0.f;
            zz = MFMA16(pah, bth[nt], zz, 0, 0, 0);
            zz = MFMA16(pah, btl[nt], zz, 0, 0, 0);
            Fq[nt][yt] = zz;
        }
    }
    __builtin_amdgcn_s_setprio(0);

    // ===== phase 2b: softmax via exp2 (unnormalized), pack A' frags, both tiles =====
    s16x8 apk[2][2];
    float inv[2];
    #pragma unroll
    for (int nt = 0; nt < 2; ++nt) {
        float mx = -3.4e38f;
        #pragma unroll
        for (int yt = 0; yt < 4; ++yt)
            #pragma unroll
            for (int r = 0; r < 4; ++r) mx = fmaxf(mx, Fq[nt][yt][r]);
        mx = fmaxf(mx, __shfl_xor(mx, 16));
        mx = fmaxf(mx, __shfl_xor(mx, 32));
        float p[4][4]; float sum = 0.f;
        #pragma unroll
        for (int yt = 0; yt < 4; ++yt)
            #pragma unroll
            for (int r = 0; r < 4; ++r) { p[yt][r] = ex2(Fq[nt][yt][r] - mx); sum += p[yt][r]; }
        sum += __shfl_xor(sum, 16);
        sum += __shfl_xor(sum, 32);
        inv[nt] = 1.0f / sum;
        #pragma unroll
        for (int ks = 0; ks < 2; ++ks) {
            union { uint32_t u[4]; s16x8 s; } A;
            A.u[0] = pkbf(p[2*ks][0],   p[2*ks][1]);
            A.u[1] = pkbf(p[2*ks][2],   p[2*ks][3]);
            A.u[2] = pkbf(p[2*ks+1][0], p[2*ks+1][1]);
            A.u[3] = pkbf(p[2*ks+1][2], p[2*ks+1][3]);
            apk[nt][ks] = A.s;
        }
    }

    // ===== phase 3: Y = G*A'^T, rescale+residual(+mask), R frag, both tiles =====
    const bool msk = spacings[b*3 + 2] <= 1.5f;
    s16x8 brf[2];
    #pragma unroll
    for (int nt = 0; nt < 2; ++nt) {
        const int zr = 32*wv + 16*nt + l15;
        f32x4v Yq[2];
        #pragma unroll
        for (int r = 0; r < 4; ++r) { Yq[0][r] = 0.f; Yq[1][r] = 0.f; }
        __builtin_amdgcn_s_setprio(1);
        #pragma unroll
        for (int ks = 0; ks < 2; ++ks) {
            #pragma unroll
            for (int mt = 0; mt < 2; ++mt) {
                const s16x8 gA = rd8(lds + OG + (16*mt + l15)*136 + 64*ks + 16*kb);
                Yq[mt] = MFMA16(gA, apk[nt][ks], Yq[mt], 0, 0, 0);
            }
        }
        __builtin_amdgcn_s_setprio(0);
        union { uint32_t u[4]; s16x8 s; } R;
        #pragma unroll
        for (int mt = 0; mt < 2; ++mt) {
            const uint64_t xh = *(const uint64_t*)(lds + OXH + zr*136 + (16*mt + 4*kb)*2);
            float rv[4];
            #pragma unroll
            for (int r = 0; r < 4; ++r) {
                const float xr = bf2f((uint16_t)(xh >> (16*r)));
                rv[r] = msk ? fmaf(Yq[mt][r], inv[nt], xr) : xr;
            }
            R.u[2*mt]   = pkbf(rv[0], rv[1]);
            R.u[2*mt+1] = pkbf(rv[2], rv[3]);
        }
        brf[nt] = R.s;
    }
    // no barrier: phase 4 touches no LDS

    // ===== phase 4: O = W*R + wb -> global (f32 or bf16); BN partials -> part =====
    {
        const s16x8 aW0 = *(const s16x8*)(frags + 8192 + l*16);
        const s16x8 aW1 = *(const s16x8*)(frags + 8192 + (64 + l)*16);
        const float4 wb0 = *(const float4*)(Wb + 4*kb);
        const float4 wb1 = *(const float4*)(Wb + 16 + 4*kb);
        #pragma unroll
        for (int nt = 0; nt < 2; ++nt) {
            const int zr = 32*wv + 16*nt + l15;
            f32x4v accs[2];
            f32x4v a0; a0[0]=wb0.x; a0[1]=wb0.y; a0[2]=wb0.z; a0[3]=wb0.w;
            f32x4v a1; a1[0]=wb1.x; a1[1]=wb1.y; a1[2]=wb1.z; a1[3]=wb1.w;
            __builtin_amdgcn_s_setprio(1);
            accs[0] = MFMA16(aW0, brf[nt], a0, 0, 0, 0);
            accs[1] = MFMA16(aW1, brf[nt], a1, 0, 0, 0);
            __builtin_amdgcn_s_setprio(0);
            if (use16) {
                unsigned short* obp = obf + base + zr;
                #pragma unroll
                for (int mt = 0; mt < 2; ++mt)
                    #pragma unroll
                    for (int r = 0; r < 4; ++r)
                        obp[(long)(16*mt + 4*kb + r)*CHS] = bfh(accs[mt][r]);
            } else {
                float* op = out + base + zr;
                #pragma unroll
                for (int mt = 0; mt < 2; ++mt)
                    #pragma unroll
                    for (int r = 0; r < 4; ++r)
                        op[(long)(16*mt + 4*kb + r)*CHS] = accs[mt][r];
            }
            const int sr = row*4 + 2*wv + nt;
            float bs[8];
            #pragma unroll
            for (int mt = 0; mt < 2; ++mt)
                #pragma unroll
                for (int r = 0; r < 4; ++r) bs[4*mt+r] = accs[mt][r];
            #pragma unroll
            for (int off = 1; off < 16; off <<= 1)
                #pragma unroll
                for (int i = 0; i < 8; ++i) bs[i] += __shfl_xor(bs[i], off);
            if (l15 == 0) {
                #pragma unroll
                for (int mt = 0; mt < 2; ++mt)
                    #pragma unroll
                    for (int r = 0; r < 4; ++r)
                        part[sr*64 + 16*mt + 4*kb + r] = bs[4*mt+r];
            }
            #pragma unroll
            for (int mt = 0; mt < 2; ++mt)
                #pragma unroll
                for (int r = 0; r < 4; ++r) { const float v = accs[mt][r]; bs[4*mt+r] = v*v; }
            #pragma unroll
            for (int off = 1; off < 16; off <<= 1)
                #pragma unroll
                for (int i = 0; i < 8; ++i) bs[i] += __shfl_xor(bs[i], off);
            if (l15 == 0) {
                #pragma unroll
                for (int mt = 0; mt < 2; ++mt)
                    #pragma unroll
                    for (int r = 0; r < 4; ++r)
                        part[sr*64 + 32 + 16*mt + 4*kb + r] = bs[4*mt+r];
            }
        }
    }
}

// stage 2a: 256 blocks, each reduces 288 sub-rows (= 72 rows x 4 z-tiles)
__global__ __launch_bounds__(256) void k2a(const float* __restrict__ part,
                                           float* __restrict__ part2)
{
    __shared__ float red[4][64];
    const int t = threadIdx.x, lane = t & 63, grp = t >> 6;
    const int p = blockIdx.x;
    float s = 0.f;
    for (int k = 0; k < 72; ++k) s += part[(p*288 + grp + 4*k)*64 + lane];
    red[grp][lane] = s;
    __syncthreads();
    if (t < 64) part2[p*64 + t] = red[0][t] + red[1][t] + red[2][t] + red[3][t];
}

// stage 2b: final reduce + BN scale/shift
__global__ __launch_bounds__(256) void k2b(const float* __restrict__ part2,
    const float* __restrict__ gamma, const float* __restrict__ beta,
    float* __restrict__ sc)
{
    __shared__ float red[4][64];
    __shared__ float tot[64];
    const int t = threadIdx.x, lane = t & 63, grp = t >> 6;
    float s = 0.f;
    for (int k = 0; k < 64; ++k) s += part2[(grp + 4*k)*64 + lane];
    red[grp][lane] = s;
    __syncthreads();
    if (t < 64) tot[t] = red[0][t] + red[1][t] + red[2][t] + red[3][t];
    __syncthreads();
    if (t < 32) {
        const float mean = tot[t] / NRED;
        const float var  = tot[32+t] / NRED - mean*mean;
        const float rstd = rsqrtf(var + 1e-5f);
        const float scale = gamma[t] * rstd;
        sc[t]    = scale;
        sc[32+t] = fmaf(-mean, scale, beta[t]);
    }
}

// stage 3 (f32 in-place): affine normalize of d_out
__global__ __launch_bounds__(256) void k3_norm(float* __restrict__ out,
                                               const float* __restrict__ sc)
{
    __shared__ float s[64];
    if (threadIdx.x < 64) s[threadIdx.x] = sc[threadIdx.x];
    __syncthreads();
    const int total4 = 2*32*CHS/4;
    const int Q = CHS/4;
    for (int i = blockIdx.x*256 + threadIdx.x; i < total4; i += gridDim.x*256) {
        float4 v = ((const float4*)out)[i];
        const int c = (i / Q) & 31;
        const float scale = s[c], shift = s[32+c];
        v.x = fmaf(v.x, scale, shift);
        v.y = fmaf(v.y, scale, shift);
        v.z = fmaf(v.z, scale, shift);
        v.w = fmaf(v.w, scale, shift);
        ((float4*)out)[i] = v;
    }
}

// stage 3 (bf16 source): read obf, affine, write f32 out
__global__ __launch_bounds__(256) void k3_norm16(const unsigned short* __restrict__ obf,
                                                 float* __restrict__ out,
                                                 const float* __restrict__ sc)
{
    __shared__ float s[64];
    if (threadIdx.x < 64) s[threadIdx.x] = sc[threadIdx.x];
    __syncthreads();
    const int total4 = 2*32*CHS/4;
    const int Q = CHS/4;
    for (int i = blockIdx.x*256 + threadIdx.x; i < total4; i += gridDim.x*256) {
        const uint2 u = *(const uint2*)(obf + (size_t)i*4);
        const int c = (i / Q) & 31;
        const float scale = s[c], shift = s[32+c];
        float4 v;
        v.x = fmaf(bf2f((uint16_t)(u.x)),        scale, shift);
        v.y = fmaf(bf2f((uint16_t)(u.x >> 16)),  scale, shift);
        v.z = fmaf(bf2f((uint16_t)(u.y)),        scale, shift);
        v.w = fmaf(bf2f((uint16_t)(u.y >> 16)),  scale, shift);
        ((float4*)out)[i] = v;
    }
}

extern "C" void kernel_launch(void* const* d_in, const int* in_sizes, int n_in,
                              void* d_out, int out_size, void* d_ws, size_t ws_size,
                              hipStream_t stream) {
    const float* x        = (const float*)d_in[0];
    const float* spacings = (const float*)d_in[1];
    const float* theta_w  = (const float*)d_in[2];
    const float* theta_b  = (const float*)d_in[3];
    const float* phi_w    = (const float*)d_in[4];
    const float* phi_b    = (const float*)d_in[5];
    const float* g_w      = (const float*)d_in[6];
    const float* g_b      = (const float*)d_in[7];
    const float* Ww       = (const float*)d_in[8];
    const float* Wb       = (const float*)d_in[9];
    const float* gamma    = (const float*)d_in[10];
    const float* beta     = (const float*)d_in[11];
    float* out   = (float*)d_out;
    char*  frags = (char*)d_ws;                         // WSFRAG bytes
    float* part  = (float*)((char*)d_ws + WSFRAG);      // ROWS*256 floats
    float* part2 = part + (size_t)ROWS*256;             // 256*64 floats
    float* sc    = part2 + 256*64;                      // 64 floats
    const size_t OBF_OFF = (size_t)WSFRAG + (size_t)ROWS*256*4 + (size_t)256*64*4 + 64*4;
    const size_t NEEDED  = OBF_OFF + (size_t)2*32*CHS*2;
    const int use16 = (ws_size >= NEEDED) ? 1 : 0;
    unsigned short* obf = (unsigned short*)((char*)d_ws + OBF_OFF);

    hipLaunchKernelGGL(k0_frag, dim3(1), dim3(256), 0, stream, theta_w, phi_w, Ww, frags);
    hipLaunchKernelGGL(k1_row, dim3(ROWS), dim3(128), 0, stream,
                       x, spacings, theta_b, phi_b, g_w, g_b, Wb, frags,
                       out, obf, use16, part);
    hipLaunchKernelGGL(k2a, dim3(256), dim3(256), 0, stream, part, part2);
    hipLaunchKernelGGL(k2b, dim3(1), dim3(256), 0, stream, part2, gamma, beta, sc);
    if (use16) {
        hipLaunchKernelGGL(k3_norm16, dim3(4096), dim3(256), 0, stream, obf, out, sc);
    } else {
        hipLaunchKernelGGL(k3_norm, dim3(4096), dim3(256), 0, stream, out, sc);
    }
}